// Round 2
// 1324.532 us; speedup vs baseline: 1.2613x; 1.2613x over previous
//
#include <hip/hip_runtime.h>
#include <math.h>
#include <stdint.h>

#define NPTS 100000
#define LKV 4
#define GYV 200
#define NBINS 40000   // GY*GY

typedef __attribute__((ext_vector_type(8))) short bf16x8;
typedef __attribute__((ext_vector_type(8))) unsigned short u16x8;
typedef __attribute__((ext_vector_type(4))) float f32x4;

// ---------- bf16 helpers (RNE) --------------------------------------------------
__device__ __forceinline__ unsigned short bfr(float f) {
    unsigned u = __float_as_uint(f);
    unsigned r = (u + 0x7fffu + ((u >> 16) & 1u)) >> 16;
    return (unsigned short)r;
}
__device__ __forceinline__ float fbf(unsigned short h) {
    return __uint_as_float(((unsigned)h) << 16);
}

// ---------- monotonic float<->uint encoding for atomicMax-based segment max ----
__device__ __forceinline__ unsigned fenc(float f) {
    unsigned u = __float_as_uint(f);
    return (u & 0x80000000u) ? ~u : (u | 0x80000000u);
}
__device__ __forceinline__ float fdec(unsigned u) {
    unsigned b = (u & 0x80000000u) ? (u & 0x7fffffffu) : ~u;
    return __uint_as_float(b);
}

// ---------- K0: zero seg/pix pool regions (as uint) + histogram bins ------------
__global__ void kZ(unsigned* __restrict__ seg_u, unsigned* __restrict__ pix_u,
                   int* __restrict__ count)
{
    size_t idx = (size_t)blockIdx.x * 256 + threadIdx.x;
    const size_t SEG = (size_t)NPTS * 256;
    if (idx < SEG)            seg_u[idx] = 0u;
    else if (idx < 2 * SEG)   pix_u[idx - SEG] = 0u;
    else if (idx < 2 * SEG + NBINS) count[idx - 2 * SEG] = 0;
}

// ---------- K1: keys + histogram ------------------------------------------------
__global__ void kH(const int* __restrict__ xy, int* __restrict__ keys,
                   int* __restrict__ count)
{
    int i = blockIdx.x * 256 + threadIdx.x;
    if (i < NPTS) {
        int key = xy[i * 2] * GYV + xy[i * 2 + 1];
        keys[i] = key;
        atomicAdd(count + key, 1);
    }
}

// ---------- K2: prefix-scan of present flags over 40000 bins (1 block) ----------
__global__ __launch_bounds__(1024) void kScan(
    const int* __restrict__ count, int* __restrict__ rank,
    int* __restrict__ unqk, int* __restrict__ total)
{
    __shared__ int swcnt[16];
    __shared__ int carry_s;
    const int t = threadIdx.x, lane = t & 63, wid = t >> 6;
    if (t == 0) carry_s = 0;
    for (int chunk = 0; chunk < 40; ++chunk) {
        __syncthreads();
        int idx = chunk * 1024 + t;
        int pres = (idx < NBINS && count[idx] > 0) ? 1 : 0;
        unsigned long long mask = __ballot(pres);
        int lanepre = __popcll(mask & ((1ull << lane) - 1ull));
        if (lane == 0) swcnt[wid] = __popcll(mask);
        __syncthreads();
        if (t == 0) {
            int s = carry_s;
            for (int w = 0; w < 16; ++w) { int cn = swcnt[w]; swcnt[w] = s; s += cn; }
            carry_s = s;
        }
        __syncthreads();
        if (pres) { int e = swcnt[wid] + lanepre; rank[idx] = e; unqk[e] = idx; }
    }
    __syncthreads();
    if (t == 0) total[0] = carry_s;
}

// ---------- KU: unq output rows -------------------------------------------------
__global__ void kU(const int* __restrict__ unqk, const int* __restrict__ total,
                   float* __restrict__ out_unq)
{
    int j = blockIdx.x * 256 + threadIdx.x;
    if (j < NPTS) {
        int k = (j < total[0]) ? unqk[j] : NBINS;
        out_unq[j * 3 + 0] = 0.f;
        out_unq[j * 3 + 1] = (float)(k / GYV);
        out_unq[j * 3 + 2] = (float)(k % GYV);
    }
}

// ---------- KConvW: fp32 [KD,OD] weight -> bf16 B-fragment order ---------------
// element (k,n) -> ((((k>>5)*(OD/16) + (n>>4))*4 + ((k>>3)&3))*16 + (n&15))*8 + (k&7)
__global__ void kConvW(const float* __restrict__ W, unsigned short* __restrict__ dst,
                       int KD, int OD)
{
    int gid = blockIdx.x * 256 + threadIdx.x;
    if (gid >= KD * OD) return;
    int k = gid / OD, n = gid - k * OD;
    int idx = ((((k >> 5) * (OD >> 4) + (n >> 4)) * 4 + ((k >> 3) & 3)) * 16 + (n & 15)) * 8 + (k & 7);
    dst[idx] = bfr(W[gid]);
}

// ---------- KConvW2: fp32 weight -> SPLIT bf16 hi/lo B-fragments ---------------
// hi = bf16(x), lo = bf16(x - hi): x ~= hi + lo to ~17 mantissa bits.
__global__ void kConvW2(const float* __restrict__ W, unsigned short* __restrict__ dh,
                        unsigned short* __restrict__ dl, int KD, int OD)
{
    int gid = blockIdx.x * 256 + threadIdx.x;
    if (gid >= KD * OD) return;
    int k = gid / OD, n = gid - k * OD;
    int idx = ((((k >> 5) * (OD >> 4) + (n >> 4)) * 4 + ((k >> 3) & 3)) * 16 + (n & 15)) * 8 + (k & 7);
    float x = W[gid];
    unsigned short h = bfr(x);
    dh[idx] = h;
    dl[idx] = bfr(x - fbf(h));
}

// ---------- MFMA accumulate: A-frag LDS [64 x KD] x B-frag global -> acc --------
// wave w owns n-tiles [w*NT, w*NT+NT); acc[mt][nt] = C tile (row mt*16.., col tile)
template <int KD, int NTILES_TOT, int NT>
__device__ __forceinline__ void mfma_acc(
    const unsigned short* __restrict__ inbuf, const unsigned short* __restrict__ wf,
    int w, int quad, int c16, f32x4 (&acc)[4][NT])
{
    constexpr int KT = KD / 32;
    const f32x4 zz = {0.f, 0.f, 0.f, 0.f};
#pragma unroll
    for (int mt = 0; mt < 4; ++mt)
#pragma unroll
        for (int nt = 0; nt < NT; ++nt) acc[mt][nt] = zz;
#pragma unroll
    for (int kt = 0; kt < KT; ++kt) {
        bf16x8 a[4], b[NT];
        const unsigned short* ap = inbuf + ((kt * 64 + c16) * 4 + quad) * 8;
#pragma unroll
        for (int mt = 0; mt < 4; ++mt) a[mt] = *reinterpret_cast<const bf16x8*>(ap + mt * 512);
#pragma unroll
        for (int nt = 0; nt < NT; ++nt) {
            const unsigned short* bp = wf +
                (size_t)(((kt * NTILES_TOT + w * NT + nt) * 4 + quad) * 16 + c16) * 8;
            b[nt] = *reinterpret_cast<const bf16x8*>(bp);
        }
#pragma unroll
        for (int mt = 0; mt < 4; ++mt)
#pragma unroll
            for (int nt = 0; nt < NT; ++nt)
                acc[mt][nt] = __builtin_amdgcn_mfma_f32_16x16x32_bf16(a[mt], b[nt], acc[mt][nt], 0, 0, 0);
    }
}

// BN+ReLU epilogue -> bf16 A-frag LDS for next layer
template <int NT>
__device__ __forceinline__ void epi_bn(
    f32x4 (&acc)[4][NT], const float* lb, const float* g, const float* bb,
    const float* m, const float* v, unsigned short* __restrict__ outbuf,
    int w, int quad, int c16)
{
#pragma unroll
    for (int nt = 0; nt < NT; ++nt) {
        int n = (w * NT + nt) * 16 + c16;
        float sc = g[n] * rsqrtf(v[n] + 1e-5f);
        float mb = m[n], bbv = bb[n], lbv = lb[n];
        int nbase = ((n >> 5) * 64) * 32 + ((n >> 3) & 3) * 8 + (n & 7);
#pragma unroll
        for (int mt = 0; mt < 4; ++mt)
#pragma unroll
            for (int r = 0; r < 4; ++r) {
                int row = mt * 16 + quad * 4 + r;
                float y = fmaxf((acc[mt][nt][r] + lbv - mb) * sc + bbv, 0.f);
                outbuf[nbase + row * 32] = bfr(y);
            }
    }
}

// ---------- KA: PPmodel via MFMA + mlp pool-atomics + q (bf16) ------------------
// block = 64 points, 4 waves; ping-pong A-frag buffers.
__global__ __launch_bounds__(256) void kA(
    const float* __restrict__ pt_fea,
    const int* __restrict__ keys, const int* __restrict__ rank,
    const float* g0, const float* b0, const float* m0, const float* v0,
    const float* W1, const float* b1, const float* g1, const float* bb1, const float* m1, const float* v1,
    const unsigned short* __restrict__ w2f, const float* b2, const float* g2, const float* bb2, const float* m2, const float* v2,
    const unsigned short* __restrict__ w3f, const float* b3, const float* g3, const float* bb3, const float* m3, const float* v3,
    const unsigned short* __restrict__ w4f, const float* b4,
    const unsigned short* __restrict__ wqf, const float* bq,
    unsigned short* __restrict__ q_out, unsigned* __restrict__ seg_u)
{
    __shared__ __attribute__((aligned(16))) unsigned short bufX[64 * 256]; // 32 KB
    __shared__ __attribute__((aligned(16))) unsigned short bufY[64 * 256]; // 32 KB
    __shared__ float ptl[64 * 3];
    __shared__ int invs[64];
    const int t = threadIdx.x, w = t >> 6, lane = t & 63;
    const int quad = lane >> 4, c16 = lane & 15;
    const int base = blockIdx.x * 64;

    if (t < 192) {   // stage pt_fea + input BN
        int p = t / 3, c = t - p * 3;
        int gp = base + p; if (gp >= NPTS) gp = NPTS - 1;
        float x = pt_fea[gp * 3 + c];
        float s = g0[c] * rsqrtf(v0[c] + 1e-5f);
        ptl[t] = (x - m0[c]) * s + b0[c];
    }
    if (t < 64 && base + t < NPTS) invs[t] = rank[keys[base + t]];
    __syncthreads();

    // ---- layer1: 3 -> 64 (fp32 VALU) -> bufX A-frag
    {
        int p = t >> 2, o0 = (t & 3) * 16;
        float x0 = ptl[p * 3], x1 = ptl[p * 3 + 1], x2 = ptl[p * 3 + 2];
#pragma unroll
        for (int j = 0; j < 16; ++j) {
            int o = o0 + j;
            float y = x0 * W1[o] + x1 * W1[64 + o] + x2 * W1[128 + o] + b1[o];
            float s = g1[o] * rsqrtf(v1[o] + 1e-5f);
            y = fmaxf((y - m1[o]) * s + bb1[o], 0.f);
            int idx = ((o >> 5) * 64 + p) * 32 + ((o >> 3) & 3) * 8 + (o & 7);
            bufX[idx] = bfr(y);
        }
    }
    __syncthreads();

    // ---- layer2: 64 -> 128
    {
        f32x4 acc[4][2];
        mfma_acc<64, 8, 2>(bufX, w2f, w, quad, c16, acc);
        epi_bn<2>(acc, b2, g2, bb2, m2, v2, bufY, w, quad, c16);
    }
    __syncthreads();

    // ---- layer3: 128 -> 256
    {
        f32x4 acc[4][4];
        mfma_acc<128, 16, 4>(bufY, w3f, w, quad, c16, acc);
        epi_bn<4>(acc, b3, g3, bb3, m3, v3, bufX, w, quad, c16);
    }
    __syncthreads();

    // ---- layer4 (mlp): 256 -> 256, atomics + bf16 A-frag for Wq
    {
        f32x4 acc[4][4];
        mfma_acc<256, 16, 4>(bufX, w4f, w, quad, c16, acc);
#pragma unroll
        for (int nt = 0; nt < 4; ++nt) {
            int n = (w * 4 + nt) * 16 + c16;
            float lbv = b4[n];
            int nbase = ((n >> 5) * 64) * 32 + ((n >> 3) & 3) * 8 + (n & 7);
#pragma unroll
            for (int mt = 0; mt < 4; ++mt)
#pragma unroll
                for (int r = 0; r < 4; ++r) {
                    int row = mt * 16 + quad * 4 + r;
                    float y = acc[mt][nt][r] + lbv;
                    bufY[nbase + row * 32] = bfr(y);
                    if (base + row < NPTS)
                        atomicMax(seg_u + (size_t)invs[row] * 256 + n, fenc(y));
                }
        }
    }
    __syncthreads();

    // ---- q = mlp @ Wq + bq -> global bf16
    {
        f32x4 acc[4][4];
        mfma_acc<256, 16, 4>(bufY, wqf, w, quad, c16, acc);
#pragma unroll
        for (int nt = 0; nt < 4; ++nt) {
            int n = (w * 4 + nt) * 16 + c16;
            float lbv = bq[n];
#pragma unroll
            for (int mt = 0; mt < 4; ++mt)
#pragma unroll
                for (int r = 0; r < 4; ++r) {
                    int row = mt * 16 + quad * 4 + r;
                    if (base + row < NPTS)
                        q_out[(size_t)(base + row) * 256 + n] = bfr(acc[mt][nt][r] + lbv);
                }
        }
    }
}

// ---------- KC1: decode pooled-mlp -> split-bf16 MFMA head, re-zero region ------
// 64 rows/block. Split precision: pooled ~= ah + al, W128 ~= bh + bl (bf16 each);
// ori = ah*bh + al*bh + ah*bl (fp32 acc) -> error ~1e-4, fp32-equivalent here.
// Blocks fully past `tot` take a constant fast path (pooled == 0 there).
__global__ __launch_bounds__(256) void kC1(
    unsigned* __restrict__ seg_u, const int* __restrict__ total,
    const unsigned short* __restrict__ w128h, const unsigned short* __restrict__ w128l,
    const float* __restrict__ b128,
    const float* __restrict__ Wc, const float* __restrict__ bc,
    float* __restrict__ out_proc)
{
    __shared__ __attribute__((aligned(16))) unsigned short sb[2 * 64 * 256]; // 64 KB
    const int t = threadIdx.x, w = t >> 6, lane = t & 63;
    const int quad = lane >> 4, c16 = lane & 15;
    const int j0 = blockIdx.x * 64;
    const int tot = total[0];

    if (j0 >= tot) {
        // all rows invalid: processed = relu(b128 @ Wc + bc), identical rows
        const int c = t & 15, r0 = (t >> 4) * 4;
        float a = bc[c];
#pragma unroll 8
        for (int k = 0; k < 128; ++k) a += b128[k] * Wc[k * 16 + c];
        a = fmaxf(a, 0.f);
#pragma unroll
        for (int rr = 0; rr < 4; ++rr) {
            int j = j0 + r0 + rr;
            if (j < NPTS) out_proc[(size_t)j * 16 + c] = a;
        }
        return;
    }

    unsigned short* fragH = sb;
    unsigned short* fragL = sb + 64 * 256;

    // ---- decode pooled mlp -> hi/lo bf16 A-frags; re-zero seg_u rows < tot
#pragma unroll
    for (int it = 0; it < 8; ++it) {
        int ch = it * 256 + t;               // chunk 0..2047 = 64 rows x 32 chunks-of-8
        int r = ch >> 5, k0 = (ch & 31) * 8;
        int j = j0 + r;
        float x[8];
        if (j < tot) {
            unsigned* src = seg_u + (size_t)j * 256 + k0;
            uint4 u0 = *reinterpret_cast<const uint4*>(src);
            uint4 u1 = *reinterpret_cast<const uint4*>(src + 4);
            x[0] = fdec(u0.x); x[1] = fdec(u0.y); x[2] = fdec(u0.z); x[3] = fdec(u0.w);
            x[4] = fdec(u1.x); x[5] = fdec(u1.y); x[6] = fdec(u1.z); x[7] = fdec(u1.w);
            uint4 z = {0u, 0u, 0u, 0u};
            *reinterpret_cast<uint4*>(src) = z;
            *reinterpret_cast<uint4*>(src + 4) = z;
        } else {
#pragma unroll
            for (int q = 0; q < 8; ++q) x[q] = 0.f;
        }
        u16x8 hv, lv;
#pragma unroll
        for (int q = 0; q < 8; ++q) {
            unsigned short h = bfr(x[q]);
            hv[q] = h;
            lv[q] = bfr(x[q] - fbf(h));
        }
        int idx = ((k0 >> 5) * 64 + r) * 32 + ((k0 >> 3) & 3) * 8;   // k0 % 8 == 0
        *reinterpret_cast<u16x8*>(fragH + idx) = hv;
        *reinterpret_cast<u16x8*>(fragL + idx) = lv;
    }
    __syncthreads();

    // ---- GEMM1: ori = pooled @ W128 + b128 (split-bf16 MFMA, 3 terms)
    f32x4 acc[4][2];
    const f32x4 zz = {0.f, 0.f, 0.f, 0.f};
#pragma unroll
    for (int mt = 0; mt < 4; ++mt)
#pragma unroll
        for (int nt = 0; nt < 2; ++nt) acc[mt][nt] = zz;
#pragma unroll
    for (int kt = 0; kt < 8; ++kt) {
        const unsigned short* aph = fragH + ((kt * 64 + c16) * 4 + quad) * 8;
        const unsigned short* apl = fragL + ((kt * 64 + c16) * 4 + quad) * 8;
        bf16x8 ah[4], al[4];
#pragma unroll
        for (int mt = 0; mt < 4; ++mt) {
            ah[mt] = *reinterpret_cast<const bf16x8*>(aph + mt * 512);
            al[mt] = *reinterpret_cast<const bf16x8*>(apl + mt * 512);
        }
#pragma unroll
        for (int nt = 0; nt < 2; ++nt) {
            size_t boff = (size_t)(((kt * 8 + w * 2 + nt) * 4 + quad) * 16 + c16) * 8;
            bf16x8 bh = *reinterpret_cast<const bf16x8*>(w128h + boff);
            bf16x8 bl = *reinterpret_cast<const bf16x8*>(w128l + boff);
#pragma unroll
            for (int mt = 0; mt < 4; ++mt) {
                acc[mt][nt] = __builtin_amdgcn_mfma_f32_16x16x32_bf16(ah[mt], bh, acc[mt][nt], 0, 0, 0);
                acc[mt][nt] = __builtin_amdgcn_mfma_f32_16x16x32_bf16(al[mt], bh, acc[mt][nt], 0, 0, 0);
                acc[mt][nt] = __builtin_amdgcn_mfma_f32_16x16x32_bf16(ah[mt], bl, acc[mt][nt], 0, 0, 0);
            }
        }
    }
    __syncthreads();   // all frag reads done -> reuse LDS for ori

    float* ori = reinterpret_cast<float*>(sb);   // [64][132] fp32, 33 KB < 64 KB
#pragma unroll
    for (int nt = 0; nt < 2; ++nt) {
        int n = (w * 2 + nt) * 16 + c16;
        float bv = b128[n];
#pragma unroll
        for (int mt = 0; mt < 4; ++mt)
#pragma unroll
            for (int r = 0; r < 4; ++r)
                ori[(mt * 16 + quad * 4 + r) * 132 + n] = acc[mt][nt][r] + bv;
    }
    __syncthreads();

    // ---- GEMM2: processed = relu(ori @ Wc + bc)  (fp32 VALU; Wc 8 KB, L1-hot)
    {
        const int c = t & 15, r0 = (t >> 4) * 4;
        float a0 = bc[c], a1 = a0, a2 = a0, a3 = a0;
#pragma unroll 8
        for (int k = 0; k < 128; ++k) {
            float wv = Wc[k * 16 + c];
            a0 += ori[(r0 + 0) * 132 + k] * wv;
            a1 += ori[(r0 + 1) * 132 + k] * wv;
            a2 += ori[(r0 + 2) * 132 + k] * wv;
            a3 += ori[(r0 + 3) * 132 + k] * wv;
        }
        // full-path blocks have j0+63 < tot+64 <= 40064 << NPTS: no bounds guard needed
        float* dst = out_proc + (size_t)(j0 + r0) * 16 + c;
        dst[0]  = fmaxf(a0, 0.f);
        dst[16] = fmaxf(a1, 0.f);
        dst[32] = fmaxf(a2, 0.f);
        dst[48] = fmaxf(a3, 0.f);
    }
}

// ---------- KP: pix pool atomics + unq_inv output -------------------------------
__global__ void kP(const float* __restrict__ pixfea,
                   const int* __restrict__ keys, const int* __restrict__ rank,
                   unsigned* __restrict__ pix_u, float* __restrict__ out_inv)
{
    size_t idx = (size_t)blockIdx.x * 256 + threadIdx.x;
    int i = (int)(idx >> 8), c = (int)(idx & 255);
    int inv = rank[keys[i]];
    atomicMax(pix_u + (size_t)inv * 256 + c, fenc(pixfea[idx]));
    if (c == 0) out_inv[i] = (float)inv;
}

// ---------- KB: bf16-MFMA fused MHA + sam pool atomics --------------------------
__global__ __launch_bounds__(256) void kB(
    const float* __restrict__ segfea, const unsigned short* __restrict__ q_in,
    const int* __restrict__ keys, const int* __restrict__ rank,
    const unsigned short* __restrict__ wkf, const unsigned short* __restrict__ wvf,
    const unsigned short* __restrict__ wof,
    const float* __restrict__ bk, const float* __restrict__ bv,
    const float* __restrict__ bo,
    unsigned* __restrict__ seg_u)
{
    __shared__ __attribute__((aligned(16))) unsigned short x_lds[64 * 256];   // 32 KB
    __shared__ __attribute__((aligned(16))) unsigned short av_lds[16 * 256];  // 8 KB
    __shared__ int invs[16];
    const int t = threadIdx.x, w = t >> 6, lane = t & 63;
    const int quad = lane >> 4, c16 = lane & 15;
    const int base = blockIdx.x * 16;

    {
        const float4* gsrc = reinterpret_cast<const float4*>(segfea + (size_t)base * 4 * 256);
#pragma unroll
        for (int it = 0; it < 16; ++it) {
            int e4 = it * 256 + t;
            float4 v4 = gsrc[e4];
            int r = e4 >> 6;
            int k0 = (e4 & 63) * 4;
            int idx = (((k0 >> 5) * 64 + r) * 4 + ((k0 >> 3) & 3)) * 8 + (k0 & 7);
            ushort4 u4;
            u4.x = bfr(v4.x); u4.y = bfr(v4.y); u4.z = bfr(v4.z); u4.w = bfr(v4.w);
            *reinterpret_cast<ushort4*>(x_lds + idx) = u4;
        }
    }
    if (t < 16) invs[t] = rank[keys[base + t]];
    __syncthreads();

    f32x4 acc[4][4];
    const f32x4 zz = {0.f, 0.f, 0.f, 0.f};

    // ================= K projection =================
    mfma_acc<256, 16, 4>(x_lds, wkf, w, quad, c16, acc);

    float bkv[4], qv[4][4];
#pragma unroll
    for (int nt = 0; nt < 4; ++nt) bkv[nt] = bk[w * 64 + nt * 16 + c16];
#pragma unroll
    for (int mt = 0; mt < 4; ++mt)
#pragma unroll
        for (int nt = 0; nt < 4; ++nt)
            qv[mt][nt] = fbf(q_in[(size_t)(base + mt * 4 + quad) * 256 + w * 64 + nt * 16 + c16]);

    float sc[4][4];
#pragma unroll
    for (int mt = 0; mt < 4; ++mt) {
#pragma unroll
        for (int r = 0; r < 4; ++r) sc[mt][r] = 0.f;
#pragma unroll
        for (int nt = 0; nt < 4; ++nt)
#pragma unroll
            for (int r = 0; r < 4; ++r)
                sc[mt][r] += (acc[mt][nt][r] + bkv[nt]) * qv[mt][nt];
    }
#pragma unroll
    for (int off = 1; off < 16; off <<= 1)
#pragma unroll
        for (int mt = 0; mt < 4; ++mt)
#pragma unroll
            for (int r = 0; r < 4; ++r) sc[mt][r] += __shfl_xor(sc[mt][r], off);

    float aw[4][4];
#pragma unroll
    for (int mt = 0; mt < 4; ++mt) {
        float mx = -INFINITY;
#pragma unroll
        for (int r = 0; r < 4; ++r) { sc[mt][r] *= 0.125f; mx = fmaxf(mx, sc[mt][r]); }
        float s = 0.f;
#pragma unroll
        for (int r = 0; r < 4; ++r) { float e = __expf(sc[mt][r] - mx); aw[mt][r] = e; s += e; }
        float inv = 1.f / s;
#pragma unroll
        for (int r = 0; r < 4; ++r) aw[mt][r] *= inv;
    }

    // ================= V projection =================
    mfma_acc<256, 16, 4>(x_lds, wvf, w, quad, c16, acc);

    float bvv[4];
#pragma unroll
    for (int nt = 0; nt < 4; ++nt) bvv[nt] = bv[w * 64 + nt * 16 + c16];
#pragma unroll
    for (int mt = 0; mt < 4; ++mt) {
#pragma unroll
        for (int nt = 0; nt < 4; ++nt) {
            float o = bvv[nt];
#pragma unroll
            for (int r = 0; r < 4; ++r) o += aw[mt][r] * acc[mt][nt][r];
            int p = mt * 4 + quad;
            int d = w * 64 + nt * 16 + c16;
            int idx = (((d >> 5) * 16 + p) * 4 + ((d >> 3) & 3)) * 8 + (d & 7);
            av_lds[idx] = bfr(o);
        }
    }
    __syncthreads();

    // ================= Wo projection =================
    f32x4 acc3[4];
#pragma unroll
    for (int nt = 0; nt < 4; ++nt) acc3[nt] = zz;
#pragma unroll
    for (int kt = 0; kt < 8; ++kt) {
        bf16x8 a = *reinterpret_cast<const bf16x8*>(av_lds + ((kt * 16 + c16) * 4 + quad) * 8);
        const unsigned short* bp = wof + (size_t)(((kt * 16 + w * 4) * 4 + quad) * 16 + c16) * 8;
#pragma unroll
        for (int nt = 0; nt < 4; ++nt) {
            bf16x8 b = *reinterpret_cast<const bf16x8*>(bp + nt * 512);
            acc3[nt] = __builtin_amdgcn_mfma_f32_16x16x32_bf16(a, b, acc3[nt], 0, 0, 0);
        }
    }
#pragma unroll
    for (int nt = 0; nt < 4; ++nt) {
        float bov = bo[w * 64 + nt * 16 + c16];
#pragma unroll
        for (int r = 0; r < 4; ++r) {
            int p = quad * 4 + r;
            float sam = acc3[nt][r] + bov;
            atomicMax(seg_u + (size_t)invs[p] * 256 + w * 64 + nt * 16 + c16, fenc(sam));
        }
    }
}

// ---------- KC2: decode seg/pix pooled regions in place -------------------------
__global__ void kC2(unsigned* __restrict__ seg_u, unsigned* __restrict__ pix_u,
                    const int* __restrict__ total)
{
    size_t idx = (size_t)blockIdx.x * 256 + threadIdx.x;
    const size_t SEG = (size_t)NPTS * 256;
    int tot = total[0];
    unsigned* buf = (idx < SEG) ? seg_u : pix_u;
    size_t k = (idx < SEG) ? idx : (idx - SEG);
    int j = (int)(k >> 8);
    if (j < tot) buf[k] = __float_as_uint(fdec(buf[k]));
}

extern "C" void kernel_launch(void* const* d_in, const int* in_sizes, int n_in,
                              void* d_out, int out_size, void* d_ws, size_t ws_size,
                              hipStream_t stream)
{
    const float* pt_fea = (const float*)d_in[0];
    const int*   xy     = (const int*)d_in[1];
    const float* segfea = (const float*)d_in[2];
    const float* pixfea = (const float*)d_in[3];
    const float* g0 = (const float*)d_in[4],  *b0 = (const float*)d_in[5];
    const float* m0 = (const float*)d_in[6],  *v0 = (const float*)d_in[7];
    const float* g1 = (const float*)d_in[8],  *bb1 = (const float*)d_in[9];
    const float* m1 = (const float*)d_in[10], *v1 = (const float*)d_in[11];
    const float* g2 = (const float*)d_in[12], *bb2 = (const float*)d_in[13];
    const float* m2 = (const float*)d_in[14], *v2 = (const float*)d_in[15];
    const float* g3 = (const float*)d_in[16], *bb3 = (const float*)d_in[17];
    const float* m3 = (const float*)d_in[18], *v3 = (const float*)d_in[19];
    const float* W1 = (const float*)d_in[20], *b1 = (const float*)d_in[21];
    const float* W2 = (const float*)d_in[22], *b2 = (const float*)d_in[23];
    const float* W3 = (const float*)d_in[24], *b3 = (const float*)d_in[25];
    const float* W4 = (const float*)d_in[26], *b4 = (const float*)d_in[27];
    const float* Wq = (const float*)d_in[28], *bq = (const float*)d_in[29];
    const float* Wk = (const float*)d_in[30], *bk = (const float*)d_in[31];
    const float* Wv = (const float*)d_in[32], *bv = (const float*)d_in[33];
    const float* Wo = (const float*)d_in[34], *bo = (const float*)d_in[35];
    const float* W128 = (const float*)d_in[36], *b128 = (const float*)d_in[37];
    const float* Wc = (const float*)d_in[38], *bc = (const float*)d_in[39];

    // d_out layout: unq[N,3] processed[N,16] seg_pooled[N,256] pix_pooled[N,256] unq_inv[N]
    float* out = (float*)d_out;
    float* out_unq  = out;
    float* out_proc = out + (size_t)NPTS * 3;
    unsigned* seg_u = (unsigned*)(out + (size_t)NPTS * 19);
    unsigned* pix_u = (unsigned*)(out + (size_t)NPTS * 275);
    float* out_inv  = out + (size_t)NPTS * 531;

    // ws layout: wf (7 matrices bf16 frag-order), q bf16 [N*256], ints, W128 hi/lo frags
    char* ws = (char*)d_ws;
    unsigned short* wf = (unsigned short*)ws;
    unsigned short* wkf = wf;                 // 65536
    unsigned short* wvf = wf + 65536;         // 65536
    unsigned short* wof = wf + 131072;        // 65536
    unsigned short* wqf = wf + 196608;        // 65536
    unsigned short* w4f = wf + 262144;        // 65536
    unsigned short* w3f = wf + 327680;        // 32768
    unsigned short* w2f = wf + 360448;        // 8192  -> total 368640
    unsigned short* q_bf = wf + 368640;
    int* keys  = (int*)(ws + (size_t)368640 * 2 + (size_t)NPTS * 256 * 2);
    int* rank  = keys + NPTS;
    int* count = rank + NBINS;
    int* unqk  = count + NBINS;
    int* total = unqk + NPTS;
    // W128 hi/lo fragment buffers: round up to 256 B so bf16x8 (16 B) loads are aligned
    uintptr_t p128 = ((uintptr_t)(total + 1) + 255u) & ~(uintptr_t)255u;
    unsigned short* w128h = (unsigned short*)p128;         // 32768 shorts (64 KB)
    unsigned short* w128l = w128h + 32768;                 // 32768 shorts (64 KB)

    const int NB16 = NPTS / 16;                      // 6250
    const int NB64 = (NPTS + 63) / 64;               // 1563
    const size_t ZTOT = 2 * (size_t)NPTS * 256 + NBINS;
    kZ<<<(int)((ZTOT + 255) / 256), 256, 0, stream>>>(seg_u, pix_u, count);
    kH<<<(NPTS + 255) / 256, 256, 0, stream>>>(xy, keys, count);
    kScan<<<1, 1024, 0, stream>>>(count, rank, unqk, total);
    kU<<<(NPTS + 255) / 256, 256, 0, stream>>>(unqk, total, out_unq);
    kConvW<<<256, 256, 0, stream>>>(Wk, wkf, 256, 256);
    kConvW<<<256, 256, 0, stream>>>(Wv, wvf, 256, 256);
    kConvW<<<256, 256, 0, stream>>>(Wo, wof, 256, 256);
    kConvW<<<256, 256, 0, stream>>>(Wq, wqf, 256, 256);
    kConvW<<<256, 256, 0, stream>>>(W4, w4f, 256, 256);
    kConvW<<<128, 256, 0, stream>>>(W3, w3f, 128, 256);
    kConvW<<<32, 256, 0, stream>>>(W2, w2f, 64, 128);
    kConvW2<<<128, 256, 0, stream>>>(W128, w128h, w128l, 256, 128);
    kA<<<NB64, 256, 0, stream>>>(pt_fea, keys, rank,
        g0, b0, m0, v0,
        W1, b1, g1, bb1, m1, v1,
        w2f, b2, g2, bb2, m2, v2,
        w3f, b3, g3, bb3, m3, v3,
        w4f, b4, wqf, bq, q_bf, seg_u);
    kC1<<<NB64, 256, 0, stream>>>(seg_u, total, w128h, w128l, b128, Wc, bc, out_proc);
    kP<<<NPTS, 256, 0, stream>>>(pixfea, keys, rank, pix_u, out_inv);
    kB<<<NB16, 256, 0, stream>>>(segfea, q_bf, keys, rank,
        wkf, wvf, wof, bk, bv, bo, seg_u);
    kC2<<<2 * NPTS, 256, 0, stream>>>(seg_u, pix_u, total);
}